// Round 1
// baseline (1006.401 us; speedup 1.0000x reference)
//
#include <hip/hip_runtime.h>

#define L_    2048
#define DIM_  3072
#define H_    24
#define D_    128
#define NQKV  9216   // 3*DIM

typedef __attribute__((ext_vector_type(8))) short bf16x8;   // 8 bf16 = 4 VGPRs
typedef __attribute__((ext_vector_type(4))) float f32x4;

__device__ __forceinline__ unsigned short f2bf(float f) {
  union { float f; unsigned u; } v; v.f = f;
  unsigned r = v.u + 0x7fffu + ((v.u >> 16) & 1u);   // RNE
  return (unsigned short)(r >> 16);
}
__device__ __forceinline__ float bf2f(unsigned short h) {
  union { unsigned u; float f; } v; v.u = ((unsigned)h) << 16;
  return v.f;
}

// ---------------------------------------------------------------- cast fp32->bf16
__global__ void cast_f32_to_bf16(const float* __restrict__ in,
                                 unsigned short* __restrict__ out, int n) {
  int total = n >> 2;
  int stride = gridDim.x * blockDim.x;
  for (int i = blockIdx.x * blockDim.x + threadIdx.x; i < total; i += stride) {
    float4 v = ((const float4*)in)[i];
    ushort4 o;
    o.x = f2bf(v.x); o.y = f2bf(v.y); o.z = f2bf(v.z); o.w = f2bf(v.w);
    ((ushort4*)out)[i] = o;
  }
}

// ---------------------------------------------------------------- bf16 MFMA GEMM
// C[M][N] = A[M][K] * B[K][N].  BM=128 BN=64 BK=64, 256 thr (4 waves),
// wave w owns rows w*32..w*32+31 (2 m-tiles of 16) x all 64 cols (4 n-tiles).
template<bool OUT_BF16, bool BIAS>
__global__ __launch_bounds__(256, 2)
void gemm_bf16(const unsigned short* __restrict__ A,
               const unsigned short* __restrict__ Bm,
               void* __restrict__ Cout,
               const float* __restrict__ bias,
               int M, int N, int K)
{
  __shared__ __align__(16) unsigned short As[128][72];  // [m][k], +8 pad (row=144B, 16B-aligned)
  __shared__ __align__(16) unsigned short Bs[64][72];   // transposed: [n][k]
  const int tid  = threadIdx.x;
  const int wave = tid >> 6;
  const int lane = tid & 63;
  const int l15  = lane & 15;
  const int quad = lane >> 4;
  const int bm = blockIdx.y * 128;
  const int bn = blockIdx.x * 64;

  f32x4 zf = {0.f, 0.f, 0.f, 0.f};
  f32x4 acc[2][4];
  #pragma unroll
  for (int i = 0; i < 2; i++)
    #pragma unroll
    for (int j = 0; j < 4; j++) acc[i][j] = zf;

  for (int k0 = 0; k0 < K; k0 += 64) {
    __syncthreads();   // protect LDS from previous iteration's reads
    // stage A tile 128x64 (8 bf16 = 16B per thread per chunk, 4 chunks)
    #pragma unroll
    for (int i = 0; i < 4; i++) {
      int linear = (i * 256 + tid) * 8;
      int r = linear >> 6;
      int c = linear & 63;
      *(uint4*)&As[r][c] = *(const uint4*)&A[(size_t)(bm + r) * K + k0 + c];
    }
    // stage B tile 64x64 transposed into Bs[n][k]
    #pragma unroll
    for (int i = 0; i < 2; i++) {
      int linear = (i * 256 + tid) * 8;
      int kk = linear >> 6;
      int nn = linear & 63;
      uint4 v = *(const uint4*)&Bm[(size_t)(k0 + kk) * N + bn + nn];
      const unsigned short* pv = (const unsigned short*)&v;
      #pragma unroll
      for (int j = 0; j < 8; j++) Bs[nn + j][kk] = pv[j];
    }
    __syncthreads();
    #pragma unroll
    for (int ks = 0; ks < 2; ks++) {   // two K=32 MFMA steps
      bf16x8 af[2], bf[4];
      #pragma unroll
      for (int mt = 0; mt < 2; mt++)
        af[mt] = *(const bf16x8*)&As[wave * 32 + mt * 16 + l15][ks * 32 + quad * 8];
      #pragma unroll
      for (int nt = 0; nt < 4; nt++)
        bf[nt] = *(const bf16x8*)&Bs[nt * 16 + l15][ks * 32 + quad * 8];
      #pragma unroll
      for (int mt = 0; mt < 2; mt++)
        #pragma unroll
        for (int nt = 0; nt < 4; nt++)
          acc[mt][nt] = __builtin_amdgcn_mfma_f32_16x16x32_bf16(
              af[mt], bf[nt], acc[mt][nt], 0, 0, 0);
    }
  }
  // epilogue: C/D layout col=lane&15, row=quad*4+reg
  #pragma unroll
  for (int mt = 0; mt < 2; mt++)
    #pragma unroll
    for (int nt = 0; nt < 4; nt++)
      #pragma unroll
      for (int r = 0; r < 4; r++) {
        int row = bm + wave * 32 + mt * 16 + quad * 4 + r;
        int col = bn + nt * 16 + l15;
        float v = acc[mt][nt][r];
        if (BIAS) v += bias[col];
        if (OUT_BF16)
          ((unsigned short*)Cout)[(size_t)row * N + col] = f2bf(v);
        else
          ((float*)Cout)[(size_t)row * N + col] = v;
      }
}

// ---------------------------------------------------------------- RMSNorm + RoPE + split
// qkv bf16 [L][9216] (cols: s*3072 + h*128 + d) -> q/k/v bf16 [H][L][D]
// 1/sqrt(D) attention scale folded into q.
__global__ __launch_bounds__(128)
void qkv_post(const unsigned short* __restrict__ qkv,
              const float* __restrict__ pe,        // [L][64][2][2]
              const float* __restrict__ q_scale,
              const float* __restrict__ k_scale,
              unsigned short* __restrict__ Qo,
              unsigned short* __restrict__ Ko,
              unsigned short* __restrict__ Vo)
{
  const int l = blockIdx.x;
  const int h = blockIdx.y;
  const int d = threadIdx.x;            // 0..127 (2 waves)
  const int wave = d >> 6;
  const unsigned short* row = qkv + (size_t)l * NQKV + h * D_;
  float qv = bf2f(row[d]);
  float kv = bf2f(row[DIM_ + d]);
  float vv = bf2f(row[2 * DIM_ + d]);
  float q2 = qv * qv, k2 = kv * kv;
  #pragma unroll
  for (int mask = 1; mask < 64; mask <<= 1) {
    q2 += __shfl_xor(q2, mask);
    k2 += __shfl_xor(k2, mask);
  }
  __shared__ float sq[2], sk[2];
  __shared__ float qbuf[128], kbuf[128];
  if ((d & 63) == 0) { sq[wave] = q2; sk[wave] = k2; }
  __syncthreads();
  float msq = (sq[0] + sq[1]) * (1.f / 128.f);
  float msk = (sk[0] + sk[1]) * (1.f / 128.f);
  float qn = qv * rsqrtf(msq + 1e-6f) * q_scale[d];
  float kn = kv * rsqrtf(msk + 1e-6f) * k_scale[d];
  qbuf[d] = qn; kbuf[d] = kn;
  __syncthreads();
  int p = d >> 1, s = d & 1;
  const float* pel = pe + (((size_t)l * 64 + p) * 2 + s) * 2;
  float a = pel[0], b = pel[1];
  float qr = (a * qbuf[2 * p] + b * qbuf[2 * p + 1]) * 0.08838834764831845f; // 1/sqrt(128)
  float kr =  a * kbuf[2 * p] + b * kbuf[2 * p + 1];
  size_t o = ((size_t)h * L_ + l) * D_ + d;
  Qo[o] = f2bf(qr);
  Ko[o] = f2bf(kr);
  Vo[o] = f2bf(vv);
}

// ---------------------------------------------------------------- flash attention
// Per block: head h, 64 queries (wave owns 16). Key tiles of 64.
// QK^T: A-frag = Q rows (regs), B-frag = K rows from LDS.
// P: C-layout -> LDS -> A-layout (guide's verified round-trip).
// PV: B-frag = V^T rows from LDS.
__global__ __launch_bounds__(256, 2)
void flash_attn(const unsigned short* __restrict__ Q,
                const unsigned short* __restrict__ K,
                const unsigned short* __restrict__ V,
                unsigned short* __restrict__ Out)  // [L][DIM] bf16
{
  __shared__ __align__(16) unsigned short Qs[64][136];
  __shared__ __align__(16) unsigned short Ks[64][136];
  __shared__ __align__(16) unsigned short Vt[128][72];   // [d][key]
  __shared__ __align__(16) unsigned short Ps[4][16][72]; // per-wave [q][key]

  const int tid  = threadIdx.x;
  const int wave = tid >> 6;
  const int lane = tid & 63;
  const int l15  = lane & 15;
  const int quad = lane >> 4;
  const int h  = blockIdx.y;
  const int q0 = blockIdx.x * 64;

  const unsigned short* Qh = Q + (size_t)h * L_ * D_;
  const unsigned short* Kh = K + (size_t)h * L_ * D_;
  const unsigned short* Vh = V + (size_t)h * L_ * D_;

  #pragma unroll
  for (int i = 0; i < 4; i++) {
    int linear = (i * 256 + tid) * 8;
    int r = linear >> 7;
    int c = linear & 127;
    *(uint4*)&Qs[r][c] = *(const uint4*)&Qh[(size_t)(q0 + r) * D_ + c];
  }
  __syncthreads();
  bf16x8 qf[4];
  #pragma unroll
  for (int kk = 0; kk < 4; kk++)
    qf[kk] = *(const bf16x8*)&Qs[wave * 16 + l15][kk * 32 + quad * 8];

  f32x4 zf = {0.f, 0.f, 0.f, 0.f};
  f32x4 oacc[8];
  #pragma unroll
  for (int i = 0; i < 8; i++) oacc[i] = zf;
  float m_i[4], l_i[4];
  #pragma unroll
  for (int r = 0; r < 4; r++) { m_i[r] = -1e30f; l_i[r] = 0.f; }

  for (int t = 0; t < L_; t += 64) {
    __syncthreads();   // previous iteration's Ks/Vt reads done
    #pragma unroll
    for (int i = 0; i < 4; i++) {
      int linear = (i * 256 + tid) * 8;
      int r = linear >> 7;
      int c = linear & 127;
      *(uint4*)&Ks[r][c] = *(const uint4*)&Kh[(size_t)(t + r) * D_ + c];
      uint4 v = *(const uint4*)&Vh[(size_t)(t + r) * D_ + c];
      const unsigned short* pv = (const unsigned short*)&v;
      #pragma unroll
      for (int j = 0; j < 8; j++) Vt[c + j][r] = pv[j];
    }
    __syncthreads();
    // S = Q K^T  (16 queries x 64 keys per wave)
    f32x4 s[4];
    #pragma unroll
    for (int nt = 0; nt < 4; nt++) {
      f32x4 a = zf;
      #pragma unroll
      for (int kk = 0; kk < 4; kk++) {
        bf16x8 kf = *(const bf16x8*)&Ks[nt * 16 + l15][kk * 32 + quad * 8];
        a = __builtin_amdgcn_mfma_f32_16x16x32_bf16(qf[kk], kf, a, 0, 0, 0);
      }
      s[nt] = a;
    }
    // online softmax; row = quad*4 + r; 16 cols/row live in the quad's 16 lanes
    float rmax[4];
    #pragma unroll
    for (int r = 0; r < 4; r++)
      rmax[r] = fmaxf(fmaxf(s[0][r], s[1][r]), fmaxf(s[2][r], s[3][r]));
    #pragma unroll
    for (int mask = 1; mask < 16; mask <<= 1)
      #pragma unroll
      for (int r = 0; r < 4; r++)
        rmax[r] = fmaxf(rmax[r], __shfl_xor(rmax[r], mask));
    float alpha[4];
    #pragma unroll
    for (int r = 0; r < 4; r++) {
      float mnew = fmaxf(m_i[r], rmax[r]);
      alpha[r] = __expf(m_i[r] - mnew);
      m_i[r] = mnew;
    }
    float rsum[4] = {0.f, 0.f, 0.f, 0.f};
    #pragma unroll
    for (int nt = 0; nt < 4; nt++)
      #pragma unroll
      for (int r = 0; r < 4; r++) {
        float p = __expf(s[nt][r] - m_i[r]);
        s[nt][r] = p;
        rsum[r] += p;
      }
    #pragma unroll
    for (int mask = 1; mask < 16; mask <<= 1)
      #pragma unroll
      for (int r = 0; r < 4; r++)
        rsum[r] += __shfl_xor(rsum[r], mask);
    #pragma unroll
    for (int r = 0; r < 4; r++)
      l_i[r] = l_i[r] * alpha[r] + rsum[r];
    #pragma unroll
    for (int n = 0; n < 8; n++)
      #pragma unroll
      for (int r = 0; r < 4; r++)
        oacc[n][r] *= alpha[r];
    // P: C-layout regs -> LDS (bf16)
    #pragma unroll
    for (int nt = 0; nt < 4; nt++)
      #pragma unroll
      for (int r = 0; r < 4; r++)
        Ps[wave][quad * 4 + r][nt * 16 + l15] = f2bf(s[nt][r]);
    __syncthreads();
    // PV: O[16 x 128] += P[16 x 64] * V[64 x 128]
    bf16x8 pf[2];
    #pragma unroll
    for (int ks = 0; ks < 2; ks++)
      pf[ks] = *(const bf16x8*)&Ps[wave][l15][ks * 32 + quad * 8];
    #pragma unroll
    for (int n = 0; n < 8; n++)
      #pragma unroll
      for (int ks = 0; ks < 2; ks++) {
        bf16x8 vf = *(const bf16x8*)&Vt[n * 16 + l15][ks * 32 + quad * 8];
        oacc[n] = __builtin_amdgcn_mfma_f32_16x16x32_bf16(pf[ks], vf, oacc[n], 0, 0, 0);
      }
  }
  // epilogue: out[l][h*128 + d], divide by row sum
  #pragma unroll
  for (int n = 0; n < 8; n++)
    #pragma unroll
    for (int r = 0; r < 4; r++) {
      int row = q0 + wave * 16 + quad * 4 + r;
      int col = h * D_ + n * 16 + l15;
      float v = oacc[n][r] / l_i[r];
      Out[(size_t)row * DIM_ + col] = f2bf(v);
    }
}

// ---------------------------------------------------------------- launcher
extern "C" void kernel_launch(void* const* d_in, const int* in_sizes, int n_in,
                              void* d_out, int out_size, void* d_ws, size_t ws_size,
                              hipStream_t stream) {
  const float* x       = (const float*)d_in[0];
  const float* pe      = (const float*)d_in[1];
  const float* w_qkv   = (const float*)d_in[2];
  const float* q_scale = (const float*)d_in[3];
  const float* k_scale = (const float*)d_in[4];
  const float* w_proj  = (const float*)d_in[5];
  const float* b_proj  = (const float*)d_in[6];

  unsigned short* w_qkv_b  = (unsigned short*)d_ws;          // 28,311,552
  unsigned short* w_proj_b = w_qkv_b + 28311552;             //  9,437,184
  unsigned short* x_b      = w_proj_b + 9437184;             //  6,291,456
  unsigned short* qkv_b    = x_b + 6291456;                  // 18,874,368
  unsigned short* q_r      = qkv_b + 18874368;               //  6,291,456
  unsigned short* k_r      = q_r + 6291456;
  unsigned short* v_r      = k_r + 6291456;
  unsigned short* attn_b   = qkv_b;   // reuse (qkv dead after qkv_post)

  cast_f32_to_bf16<<<2048, 256, 0, stream>>>(x, x_b, 6291456);
  cast_f32_to_bf16<<<2048, 256, 0, stream>>>(w_qkv, w_qkv_b, 28311552);
  cast_f32_to_bf16<<<2048, 256, 0, stream>>>(w_proj, w_proj_b, 9437184);

  gemm_bf16<true, false><<<dim3(144, 16), 256, 0, stream>>>(
      x_b, w_qkv_b, qkv_b, nullptr, 2048, 9216, 3072);

  qkv_post<<<dim3(2048, 24), 128, 0, stream>>>(
      qkv_b, pe, q_scale, k_scale, q_r, k_r, v_r);

  flash_attn<<<dim3(32, 24), 256, 0, stream>>>(q_r, k_r, v_r, attn_b);

  gemm_bf16<false, true><<<dim3(48, 16), 256, 0, stream>>>(
      attn_b, w_proj_b, d_out, b_proj, 2048, 3072, 3072);
}

// Round 2
// 616.410 us; speedup vs baseline: 1.6327x; 1.6327x over previous
//
#include <hip/hip_runtime.h>

#define L_    2048
#define DIM_  3072
#define H_    24
#define D_    128
#define NQKV  9216   // 3*DIM

typedef __attribute__((ext_vector_type(8))) short bf16x8;   // 8 bf16 = 4 VGPRs
typedef __attribute__((ext_vector_type(4))) float f32x4;

__device__ __forceinline__ unsigned short f2bf(float f) {
  union { float f; unsigned u; } v; v.f = f;
  unsigned r = v.u + 0x7fffu + ((v.u >> 16) & 1u);   // RNE
  return (unsigned short)(r >> 16);
}
__device__ __forceinline__ float bf2f(unsigned short h) {
  union { unsigned u; float f; } v; v.u = ((unsigned)h) << 16;
  return v.f;
}

// async global->LDS, 16B per lane. LDS dest = wave-uniform base + lane*16.
__device__ __forceinline__ void gload_lds16(const void* g, void* l) {
  auto* lp = reinterpret_cast<__attribute__((address_space(3))) unsigned int*>(
      reinterpret_cast<uintptr_t>(l));
  auto* gp = reinterpret_cast<const __attribute__((address_space(1))) unsigned int*>(
      reinterpret_cast<uintptr_t>(g));
  __builtin_amdgcn_global_load_lds(gp, lp, 16, 0, 0);
}

// ---------------------------------------------------------------- cast fp32->bf16
__global__ void cast_f32_to_bf16(const float* __restrict__ in,
                                 unsigned short* __restrict__ out, int n) {
  int total = n >> 2;
  int stride = gridDim.x * blockDim.x;
  for (int i = blockIdx.x * blockDim.x + threadIdx.x; i < total; i += stride) {
    float4 v = ((const float4*)in)[i];
    ushort4 o;
    o.x = f2bf(v.x); o.y = f2bf(v.y); o.z = f2bf(v.z); o.w = f2bf(v.w);
    ((ushort4*)out)[i] = o;
  }
}

// ---------------------------------------------------------------- cast + transpose
// in[K][N] fp32 -> out[N][K] bf16.  Lanes along k => coalesced writes; each
// lane streams 128 consecutive n's (L1 catches the strided read lines).
__global__ __launch_bounds__(256)
void castT_f32_bf16(const float* __restrict__ in, unsigned short* __restrict__ out,
                    int K, int N) {
  int k = blockIdx.x * 256 + threadIdx.x;
  int n0 = blockIdx.y * 128;
  const float* src = in + (size_t)k * N;
  #pragma unroll 8
  for (int j = 0; j < 128; j++)
    out[(size_t)(n0 + j) * K + k] = f2bf(src[n0 + j]);
}

// ---------------------------------------------------------------- bf16 MFMA GEMM
// C[M][N] = A[M][K] * Bt[N][K]^T.  128x128 tile, BK=64, 256 thr (4 waves),
// wave (wm,wn) owns a 64x64 quadrant (4x4 tiles of 16x16).
// LDS tiles 128 rows x 64 shorts, XOR-swizzled 16B chunks: phys = log ^ (row&7).
template<bool OUT_BF16, bool BIAS>
__global__ __launch_bounds__(256, 2)
void gemm_bt(const unsigned short* __restrict__ A,
             const unsigned short* __restrict__ Bt,
             void* __restrict__ Cout, const float* __restrict__ bias,
             int M, int N, int K)
{
  __shared__ unsigned short As[128 * 64];
  __shared__ unsigned short Bs[128 * 64];
  const int tid  = threadIdx.x;
  const int wave = tid >> 6;
  const int lane = tid & 63;
  const int l15  = lane & 15;
  const int quad = lane >> 4;
  const int wm = wave >> 1, wn = wave & 1;
  const int bm = blockIdx.y * 128;
  const int bn = blockIdx.x * 128;

  // staging geometry: 1024B per instr = 8 rows x 8 chunks; lane i -> row i>>3,
  // phys chunk i&7, logical chunk (i&7)^(i>>3)  [row&7 == i>>3].
  const int srow = lane >> 3;
  const int scol = (lane & 7) ^ srow;
  const unsigned short* Ag = A  + (size_t)(bm + wave * 32 + srow) * K + scol * 8;
  const unsigned short* Bg = Bt + (size_t)(bn + wave * 32 + srow) * K + scol * 8;
  unsigned short* Al = &As[(wave * 32) * 64];
  unsigned short* Bl = &Bs[(wave * 32) * 64];

  f32x4 acc[4][4];
  #pragma unroll
  for (int i = 0; i < 4; i++)
    #pragma unroll
    for (int j = 0; j < 4; j++) acc[i][j] = (f32x4){0.f, 0.f, 0.f, 0.f};

  for (int k0 = 0; k0 < K; k0 += 64) {
    __syncthreads();
    #pragma unroll
    for (int j = 0; j < 4; j++) {
      gload_lds16(Ag + (size_t)j * 8 * K + k0, Al + j * 8 * 64);
      gload_lds16(Bg + (size_t)j * 8 * K + k0, Bl + j * 8 * 64);
    }
    __syncthreads();   // drains vmcnt -> LDS-DMA data visible
    #pragma unroll
    for (int ks = 0; ks < 2; ks++) {
      const int cph = ((ks * 4 + quad) ^ (l15 & 7)) * 8;
      bf16x8 af[4], bf[4];
      #pragma unroll
      for (int mt = 0; mt < 4; mt++)
        af[mt] = *(const bf16x8*)&As[(wm * 64 + mt * 16 + l15) * 64 + cph];
      #pragma unroll
      for (int nt = 0; nt < 4; nt++)
        bf[nt] = *(const bf16x8*)&Bs[(wn * 64 + nt * 16 + l15) * 64 + cph];
      #pragma unroll
      for (int mt = 0; mt < 4; mt++)
        #pragma unroll
        for (int nt = 0; nt < 4; nt++)
          acc[mt][nt] = __builtin_amdgcn_mfma_f32_16x16x32_bf16(
              af[mt], bf[nt], acc[mt][nt], 0, 0, 0);
    }
  }
  // epilogue: C/D layout col=lane&15, row=quad*4+reg
  #pragma unroll
  for (int mt = 0; mt < 4; mt++)
    #pragma unroll
    for (int nt = 0; nt < 4; nt++)
      #pragma unroll
      for (int r = 0; r < 4; r++) {
        int row = bm + wm * 64 + mt * 16 + quad * 4 + r;
        int col = bn + wn * 64 + nt * 16 + l15;
        float v = acc[mt][nt][r];
        if (BIAS) v += bias[col];
        if (OUT_BF16)
          ((unsigned short*)Cout)[(size_t)row * N + col] = f2bf(v);
        else
          ((float*)Cout)[(size_t)row * N + col] = v;
      }
}

// ---------------------------------------------------------------- RMSNorm + RoPE (Q,K)
__global__ __launch_bounds__(128)
void qkv_post(const unsigned short* __restrict__ qkv,
              const float* __restrict__ pe,        // [L][64][2][2]
              const float* __restrict__ q_scale,
              const float* __restrict__ k_scale,
              unsigned short* __restrict__ Qo,     // [H][L][D]
              unsigned short* __restrict__ Ko)     // [H][L][D]
{
  const int l = blockIdx.x;
  const int h = blockIdx.y;
  const int d = threadIdx.x;            // 0..127 (2 waves)
  const int wave = d >> 6;
  const unsigned short* row = qkv + (size_t)l * NQKV + h * D_;
  float qv = bf2f(row[d]);
  float kv = bf2f(row[DIM_ + d]);
  float q2 = qv * qv, k2 = kv * kv;
  #pragma unroll
  for (int mask = 1; mask < 64; mask <<= 1) {
    q2 += __shfl_xor(q2, mask);
    k2 += __shfl_xor(k2, mask);
  }
  __shared__ float sq[2], sk[2];
  __shared__ float qbuf[128], kbuf[128];
  if ((d & 63) == 0) { sq[wave] = q2; sk[wave] = k2; }
  __syncthreads();
  float msq = (sq[0] + sq[1]) * (1.f / 128.f);
  float msk = (sk[0] + sk[1]) * (1.f / 128.f);
  qbuf[d] = qv * rsqrtf(msq + 1e-6f) * q_scale[d];
  kbuf[d] = kv * rsqrtf(msk + 1e-6f) * k_scale[d];
  __syncthreads();
  int p = d >> 1, s = d & 1;
  const float* pel = pe + (((size_t)l * 64 + p) * 2 + s) * 2;
  float a = pel[0], b = pel[1];
  float qr = (a * qbuf[2 * p] + b * qbuf[2 * p + 1]) * 0.08838834764831845f; // 1/sqrt(128)
  float kr =  a * kbuf[2 * p] + b * kbuf[2 * p + 1];
  size_t o = ((size_t)h * L_ + l) * D_ + d;
  Qo[o] = f2bf(qr);
  Ko[o] = f2bf(kr);
}

// ---------------------------------------------------------------- V transpose
// qkv[l][2*DIM + h*128 + d] -> Vt[h][d][l].  Lane = l: writes coalesced along
// Vt rows; each lane streams its own 256B of qkv (L1-served).
__global__ __launch_bounds__(256)
void v_transpose(const unsigned short* __restrict__ qkv,
                 unsigned short* __restrict__ Vt) {
  int h = blockIdx.y;
  int l = blockIdx.x * 256 + threadIdx.x;
  const unsigned short* src = qkv + (size_t)l * NQKV + 2 * DIM_ + h * D_;
  unsigned short* dst = Vt + (size_t)h * D_ * L_ + l;
  #pragma unroll
  for (int c = 0; c < 16; c++) {
    uint4 v = *(const uint4*)&src[c * 8];
    const unsigned short* pv = (const unsigned short*)&v;
    #pragma unroll
    for (int j = 0; j < 8; j++)
      dst[(size_t)(c * 8 + j) * L_] = pv[j];
  }
}

// ---------------------------------------------------------------- flash attention
// Block: 2 waves, 64 queries (32/wave), one head. Key tiles of 64.
// K staged [key][d] (256B rows, 16-chunk swizzle), V staged from global Vt
// [d][key] (128B rows, 8-chunk swizzle), both via global_load_lds.
__global__ __launch_bounds__(128, 2)
void flash_attn(const unsigned short* __restrict__ Q,   // [H][L][D]
                const unsigned short* __restrict__ K,   // [H][L][D]
                const unsigned short* __restrict__ Vt,  // [H][D][L]
                unsigned short* __restrict__ Out)       // [L][DIM]
{
  __shared__ unsigned short Ks[64 * 128];
  __shared__ unsigned short Vs[128 * 64];
  __shared__ unsigned short Ps[2][32 * 72];   // per-wave [q][key], +8 pad
  const int tid  = threadIdx.x;
  const int wave = tid >> 6;
  const int lane = tid & 63;
  const int l15  = lane & 15;
  const int quad = lane >> 4;
  const int h  = blockIdx.y;
  const int qw = blockIdx.x * 64 + wave * 32;

  const unsigned short* Qh = Q  + (size_t)h * L_ * D_;
  const unsigned short* Kh = K  + (size_t)h * L_ * D_;
  const unsigned short* Vh = Vt + (size_t)h * D_ * L_;

  // Q fragments direct from global (A-layout: m=l15, k=quad*8+j)
  bf16x8 qf[2][4];
  #pragma unroll
  for (int mt = 0; mt < 2; mt++)
    #pragma unroll
    for (int kc = 0; kc < 4; kc++)
      qf[mt][kc] = *(const bf16x8*)&Qh[(size_t)(qw + mt * 16 + l15) * D_ + kc * 32 + quad * 8];

  // staging lane geometry
  const int k_row = lane >> 4;          // Ks: 4 rows x 16 chunks per instr
  const int k_cph = lane & 15;
  const int v_row = lane >> 3;          // Vs: 8 rows x 8 chunks per instr
  const int v_cl  = (lane & 7) ^ v_row;

  f32x4 oacc[2][8];
  #pragma unroll
  for (int i = 0; i < 2; i++)
    #pragma unroll
    for (int j = 0; j < 8; j++) oacc[i][j] = (f32x4){0.f, 0.f, 0.f, 0.f};
  float m_i[2][4], l_i[2][4];
  #pragma unroll
  for (int i = 0; i < 2; i++)
    #pragma unroll
    for (int r = 0; r < 4; r++) { m_i[i][r] = -1e30f; l_i[i][r] = 0.f; }

  for (int t = 0; t < L_; t += 64) {
    __syncthreads();   // prev iteration's Ks/Vs reads done
    #pragma unroll
    for (int j = 0; j < 8; j++) {
      int R  = wave * 32 + j * 4;                 // Ks rows
      int rl = (R & 15) | k_row;                  // (R + k_row) & 15
      int cl = k_cph ^ rl;
      gload_lds16(&Kh[(size_t)(t + R + k_row) * D_ + cl * 8], &Ks[R * 128]);
      int R2 = wave * 64 + j * 8;                 // Vs rows (d)
      gload_lds16(&Vh[(size_t)(R2 + v_row) * L_ + t + v_cl * 8], &Vs[R2 * 64]);
    }
    __syncthreads();   // drain LDS-DMA

    // S = Q K^T : 32q x 64key per wave
    f32x4 s[2][4];
    #pragma unroll
    for (int i = 0; i < 2; i++)
      #pragma unroll
      for (int j = 0; j < 4; j++) s[i][j] = (f32x4){0.f, 0.f, 0.f, 0.f};
    #pragma unroll
    for (int nt = 0; nt < 4; nt++) {
      const int krow = nt * 16 + l15;
      #pragma unroll
      for (int kc = 0; kc < 4; kc++) {
        bf16x8 kf = *(const bf16x8*)&Ks[krow * 128 + (((kc * 4 + quad) ^ l15) * 8)];
        s[0][nt] = __builtin_amdgcn_mfma_f32_16x16x32_bf16(qf[0][kc], kf, s[0][nt], 0, 0, 0);
        s[1][nt] = __builtin_amdgcn_mfma_f32_16x16x32_bf16(qf[1][kc], kf, s[1][nt], 0, 0, 0);
      }
    }
    // online softmax (rows live across the 16-lane quad group)
    #pragma unroll
    for (int mt = 0; mt < 2; mt++) {
      float rmax[4], alpha[4], rsum[4];
      #pragma unroll
      for (int r = 0; r < 4; r++)
        rmax[r] = fmaxf(fmaxf(s[mt][0][r], s[mt][1][r]), fmaxf(s[mt][2][r], s[mt][3][r]));
      #pragma unroll
      for (int m = 1; m < 16; m <<= 1)
        #pragma unroll
        for (int r = 0; r < 4; r++)
          rmax[r] = fmaxf(rmax[r], __shfl_xor(rmax[r], m));
      #pragma unroll
      for (int r = 0; r < 4; r++) {
        float mnew = fmaxf(m_i[mt][r], rmax[r]);
        alpha[r] = __expf(m_i[mt][r] - mnew);
        m_i[mt][r] = mnew;
        rsum[r] = 0.f;
      }
      #pragma unroll
      for (int nt = 0; nt < 4; nt++)
        #pragma unroll
        for (int r = 0; r < 4; r++) {
          float p = __expf(s[mt][nt][r] - m_i[mt][r]);
          rsum[r] += p;
          Ps[wave][(mt * 16 + quad * 4 + r) * 72 + nt * 16 + l15] = f2bf(p);
        }
      #pragma unroll
      for (int m = 1; m < 16; m <<= 1)
        #pragma unroll
        for (int r = 0; r < 4; r++)
          rsum[r] += __shfl_xor(rsum[r], m);
      #pragma unroll
      for (int r = 0; r < 4; r++)
        l_i[mt][r] = l_i[mt][r] * alpha[r] + rsum[r];
      #pragma unroll
      for (int nt = 0; nt < 8; nt++)
        #pragma unroll
        for (int r = 0; r < 4; r++)
          oacc[mt][nt][r] *= alpha[r];
    }
    asm volatile("s_waitcnt lgkmcnt(0)" ::: "memory");  // wave-local: Ps visible
    // P fragments (A-layout)
    bf16x8 pf[2][2];
    #pragma unroll
    for (int mt = 0; mt < 2; mt++)
      #pragma unroll
      for (int ks = 0; ks < 2; ks++)
        pf[mt][ks] = *(const bf16x8*)&Ps[wave][(mt * 16 + l15) * 72 + (ks * 4 + quad) * 8];
    // O += P V : B-frag from Vs[d][key]
    #pragma unroll
    for (int nt = 0; nt < 8; nt++) {
      const int vrow = nt * 16 + l15;
      #pragma unroll
      for (int ks = 0; ks < 2; ks++) {
        bf16x8 vf = *(const bf16x8*)&Vs[vrow * 64 + (((ks * 4 + quad) ^ (l15 & 7)) * 8)];
        oacc[0][nt] = __builtin_amdgcn_mfma_f32_16x16x32_bf16(pf[0][ks], vf, oacc[0][nt], 0, 0, 0);
        oacc[1][nt] = __builtin_amdgcn_mfma_f32_16x16x32_bf16(pf[1][ks], vf, oacc[1][nt], 0, 0, 0);
      }
    }
  }
  // epilogue
  #pragma unroll
  for (int mt = 0; mt < 2; mt++)
    #pragma unroll
    for (int nt = 0; nt < 8; nt++)
      #pragma unroll
      for (int r = 0; r < 4; r++) {
        int row = qw + mt * 16 + quad * 4 + r;
        int col = h * D_ + nt * 16 + l15;
        Out[(size_t)row * DIM_ + col] = f2bf(oacc[mt][nt][r] / l_i[mt][r]);
      }
}

// ---------------------------------------------------------------- launcher
extern "C" void kernel_launch(void* const* d_in, const int* in_sizes, int n_in,
                              void* d_out, int out_size, void* d_ws, size_t ws_size,
                              hipStream_t stream) {
  const float* x       = (const float*)d_in[0];
  const float* pe      = (const float*)d_in[1];
  const float* w_qkv   = (const float*)d_in[2];
  const float* q_scale = (const float*)d_in[3];
  const float* k_scale = (const float*)d_in[4];
  const float* w_proj  = (const float*)d_in[5];
  const float* b_proj  = (const float*)d_in[6];

  unsigned short* w_qkvT  = (unsigned short*)d_ws;           // [9216][3072]
  unsigned short* w_projT = w_qkvT + 28311552;               // [3072][3072]
  unsigned short* x_b     = w_projT + 9437184;               // [2048][3072]
  unsigned short* qkv_b   = x_b + 6291456;                   // [2048][9216]
  unsigned short* q_r     = qkv_b + 18874368;                // [H][L][D]
  unsigned short* k_r     = q_r + 6291456;
  unsigned short* vt_r    = k_r + 6291456;                   // [H][D][L]
  unsigned short* attn_b  = qkv_b;   // reuse (qkv dead after v_transpose)

  cast_f32_to_bf16<<<2048, 256, 0, stream>>>(x, x_b, 6291456);
  castT_f32_bf16<<<dim3(12, 72), 256, 0, stream>>>(w_qkv, w_qkvT, 3072, 9216);
  castT_f32_bf16<<<dim3(12, 24), 256, 0, stream>>>(w_proj, w_projT, 3072, 3072);

  gemm_bt<true, false><<<dim3(72, 16), 256, 0, stream>>>(
      x_b, w_qkvT, qkv_b, nullptr, 2048, 9216, 3072);

  qkv_post<<<dim3(2048, 24), 128, 0, stream>>>(
      qkv_b, pe, q_scale, k_scale, q_r, k_r);
  v_transpose<<<dim3(8, 24), 256, 0, stream>>>(qkv_b, vt_r);

  flash_attn<<<dim3(32, 24), 128, 0, stream>>>(q_r, k_r, vt_r, attn_b);

  gemm_bt<false, true><<<dim3(24, 16), 256, 0, stream>>>(
      attn_b, w_projT, d_out, b_proj, 2048, 3072, 3072);
}

// Round 3
// 559.462 us; speedup vs baseline: 1.7989x; 1.1018x over previous
//
#include <hip/hip_runtime.h>

#define L_    2048
#define DIM_  3072
#define H_    24
#define D_    128
#define NQKV  9216   // 3*DIM

typedef __attribute__((ext_vector_type(8))) short bf16x8;   // 8 bf16 = 4 VGPRs
typedef __attribute__((ext_vector_type(4))) short bf16x4;   // 4 bf16 = 2 VGPRs
typedef __attribute__((ext_vector_type(4))) float f32x4;

__device__ __forceinline__ unsigned short f2bf(float f) {
  union { float f; unsigned u; } v; v.f = f;
  unsigned r = v.u + 0x7fffu + ((v.u >> 16) & 1u);   // RNE
  return (unsigned short)(r >> 16);
}
__device__ __forceinline__ float bf2f(unsigned short h) {
  union { unsigned u; float f; } v; v.u = ((unsigned)h) << 16;
  return v.f;
}

// async global->LDS, 16B per lane. LDS dest = wave-uniform base + lane*16.
__device__ __forceinline__ void gload_lds16(const void* g, void* l) {
  auto* lp = reinterpret_cast<__attribute__((address_space(3))) unsigned int*>(
      reinterpret_cast<uintptr_t>(l));
  auto* gp = reinterpret_cast<const __attribute__((address_space(1))) unsigned int*>(
      reinterpret_cast<uintptr_t>(g));
  __builtin_amdgcn_global_load_lds(gp, lp, 16, 0, 0);
}

// ---------------------------------------------------------------- cast fp32->bf16
__global__ void cast_f32_to_bf16(const float* __restrict__ in,
                                 unsigned short* __restrict__ out, int n) {
  int total = n >> 2;
  int stride = gridDim.x * blockDim.x;
  for (int i = blockIdx.x * blockDim.x + threadIdx.x; i < total; i += stride) {
    float4 v = ((const float4*)in)[i];
    ushort4 o;
    o.x = f2bf(v.x); o.y = f2bf(v.y); o.z = f2bf(v.z); o.w = f2bf(v.w);
    ((ushort4*)out)[i] = o;
  }
}

// ---------------------------------------------------------------- cast + transpose
__global__ __launch_bounds__(256)
void castT_f32_bf16(const float* __restrict__ in, unsigned short* __restrict__ out,
                    int K, int N) {
  int k = blockIdx.x * 256 + threadIdx.x;
  int n0 = blockIdx.y * 128;
  const float* src = in + (size_t)k * N;
  #pragma unroll 8
  for (int j = 0; j < 128; j++)
    out[(size_t)(n0 + j) * K + k] = f2bf(src[n0 + j]);
}

// ---------------------------------------------------------------- bf16 MFMA GEMM
// C[M][N] = A[M][K] * Bt[N][K]^T.  128x128 tile, BK=64, 256 thr (4 waves).
template<bool OUT_BF16, bool BIAS>
__global__ __launch_bounds__(256, 3)
void gemm_bt(const unsigned short* __restrict__ A,
             const unsigned short* __restrict__ Bt,
             void* __restrict__ Cout, const float* __restrict__ bias,
             int M, int N, int K)
{
  __shared__ unsigned short As[128 * 64];
  __shared__ unsigned short Bs[128 * 64];
  const int tid  = threadIdx.x;
  const int wave = tid >> 6;
  const int lane = tid & 63;
  const int l15  = lane & 15;
  const int quad = lane >> 4;
  const int wm = wave >> 1, wn = wave & 1;
  const int bm = blockIdx.y * 128;
  const int bn = blockIdx.x * 128;

  const int srow = lane >> 3;
  const int scol = (lane & 7) ^ srow;
  const unsigned short* Ag = A  + (size_t)(bm + wave * 32 + srow) * K + scol * 8;
  const unsigned short* Bg = Bt + (size_t)(bn + wave * 32 + srow) * K + scol * 8;
  unsigned short* Al = &As[(wave * 32) * 64];
  unsigned short* Bl = &Bs[(wave * 32) * 64];

  f32x4 acc[4][4];
  #pragma unroll
  for (int i = 0; i < 4; i++)
    #pragma unroll
    for (int j = 0; j < 4; j++) acc[i][j] = (f32x4){0.f, 0.f, 0.f, 0.f};

  for (int k0 = 0; k0 < K; k0 += 64) {
    __syncthreads();
    #pragma unroll
    for (int j = 0; j < 4; j++) {
      gload_lds16(Ag + (size_t)j * 8 * K + k0, Al + j * 8 * 64);
      gload_lds16(Bg + (size_t)j * 8 * K + k0, Bl + j * 8 * 64);
    }
    __syncthreads();
    #pragma unroll
    for (int ks = 0; ks < 2; ks++) {
      const int cph = ((ks * 4 + quad) ^ (l15 & 7)) * 8;
      bf16x8 af[4], bf[4];
      #pragma unroll
      for (int mt = 0; mt < 4; mt++)
        af[mt] = *(const bf16x8*)&As[(wm * 64 + mt * 16 + l15) * 64 + cph];
      #pragma unroll
      for (int nt = 0; nt < 4; nt++)
        bf[nt] = *(const bf16x8*)&Bs[(wn * 64 + nt * 16 + l15) * 64 + cph];
      #pragma unroll
      for (int mt = 0; mt < 4; mt++)
        #pragma unroll
        for (int nt = 0; nt < 4; nt++)
          acc[mt][nt] = __builtin_amdgcn_mfma_f32_16x16x32_bf16(
              af[mt], bf[nt], acc[mt][nt], 0, 0, 0);
    }
  }
  #pragma unroll
  for (int mt = 0; mt < 4; mt++)
    #pragma unroll
    for (int nt = 0; nt < 4; nt++)
      #pragma unroll
      for (int r = 0; r < 4; r++) {
        int row = bm + wm * 64 + mt * 16 + quad * 4 + r;
        int col = bn + wn * 64 + nt * 16 + l15;
        float v = acc[mt][nt][r];
        if (BIAS) v += bias[col];
        if (OUT_BF16)
          ((unsigned short*)Cout)[(size_t)row * N + col] = f2bf(v);
        else
          ((float*)Cout)[(size_t)row * N + col] = v;
      }
}

// ---------------------------------------------------------------- RMSNorm + RoPE (Q,K)
__global__ __launch_bounds__(128)
void qkv_post(const unsigned short* __restrict__ qkv,
              const float* __restrict__ pe,        // [L][64][2][2]
              const float* __restrict__ q_scale,
              const float* __restrict__ k_scale,
              unsigned short* __restrict__ Qo,     // [H][L][D]
              unsigned short* __restrict__ Ko)     // [H][L][D]
{
  const int l = blockIdx.x;
  const int h = blockIdx.y;
  const int d = threadIdx.x;
  const int wave = d >> 6;
  const unsigned short* row = qkv + (size_t)l * NQKV + h * D_;
  float qv = bf2f(row[d]);
  float kv = bf2f(row[DIM_ + d]);
  float q2 = qv * qv, k2 = kv * kv;
  #pragma unroll
  for (int mask = 1; mask < 64; mask <<= 1) {
    q2 += __shfl_xor(q2, mask);
    k2 += __shfl_xor(k2, mask);
  }
  __shared__ float sq[2], sk[2];
  __shared__ float qbuf[128], kbuf[128];
  if ((d & 63) == 0) { sq[wave] = q2; sk[wave] = k2; }
  __syncthreads();
  float msq = (sq[0] + sq[1]) * (1.f / 128.f);
  float msk = (sk[0] + sk[1]) * (1.f / 128.f);
  qbuf[d] = qv * rsqrtf(msq + 1e-6f) * q_scale[d];
  kbuf[d] = kv * rsqrtf(msk + 1e-6f) * k_scale[d];
  __syncthreads();
  int p = d >> 1, s = d & 1;
  const float* pel = pe + (((size_t)l * 64 + p) * 2 + s) * 2;
  float a = pel[0], b = pel[1];
  float qr = (a * qbuf[2 * p] + b * qbuf[2 * p + 1]) * 0.08838834764831845f;
  float kr =  a * kbuf[2 * p] + b * kbuf[2 * p + 1];
  size_t o = ((size_t)h * L_ + l) * D_ + d;
  Qo[o] = f2bf(qr);
  Ko[o] = f2bf(kr);
}

// ---------------------------------------------------------------- V transpose
__global__ __launch_bounds__(256)
void v_transpose(const unsigned short* __restrict__ qkv,
                 unsigned short* __restrict__ Vt) {
  int h = blockIdx.y;
  int l = blockIdx.x * 256 + threadIdx.x;
  const unsigned short* src = qkv + (size_t)l * NQKV + 2 * DIM_ + h * D_;
  unsigned short* dst = Vt + (size_t)h * D_ * L_ + l;
  #pragma unroll
  for (int c = 0; c < 16; c++) {
    uint4 v = *(const uint4*)&src[c * 8];
    const unsigned short* pv = (const unsigned short*)&v;
    #pragma unroll
    for (int j = 0; j < 8; j++)
      dst[(size_t)(c * 8 + j) * L_] = pv[j];
  }
}

// ---------------------------------------------------------------- flash attention v3
// Block: 4 waves, 64 queries, one head. Wave = (qg, kh): q-group of 32,
// key-half of the shared 64-key tile. S^T = K*Q^T so softmax is lane-indexed
// (q = l15) and P stays in registers as A-frags for mfma_16x16x16 PV.
// End-of-kernel LDS merge combines the two key-halves per q-group.
__global__ __launch_bounds__(256, 3)
void flash_attn(const unsigned short* __restrict__ Q,   // [H][L][D]
                const unsigned short* __restrict__ K,   // [H][L][D]
                const unsigned short* __restrict__ Vt,  // [H][D][L]
                unsigned short* __restrict__ Out)       // [L][DIM]
{
  __shared__ __align__(16) char smem[34304];
  unsigned short* Ks = (unsigned short*)smem;          // [64][128] swizzled(16)
  unsigned short* Vs = Ks + 8192;                      // [128][64] swizzled(8)
  float*  Obuf = (float*)smem;                         // merge: [2][32][128]
  float2* mlb  = (float2*)(smem + 32768);              // [2*32]
  float4* sAr  = (float4*)(smem + 33280);              // [2*32]

  const int tid  = threadIdx.x;
  const int wave = tid >> 6;
  const int lane = tid & 63;
  const int l15  = lane & 15;
  const int quad = lane >> 4;
  const int qg = wave >> 1;            // query group (32 q)
  const int kh = wave & 1;             // key half (32 keys of the 64-tile)
  const int h  = blockIdx.y;
  const int q0 = blockIdx.x * 64 + qg * 32;

  const unsigned short* Qh = Q  + (size_t)h * L_ * D_;
  const unsigned short* Kh = K  + (size_t)h * L_ * D_;
  const unsigned short* Vh = Vt + (size_t)h * D_ * L_;

  // Q as B-frags: B[k=d][n=q] -> lane reads Q[q0+nt*16+l15][kc*32+quad*8..+7]
  bf16x8 qf[2][4];
  #pragma unroll
  for (int nt = 0; nt < 2; nt++)
    #pragma unroll
    for (int kc = 0; kc < 4; kc++)
      qf[nt][kc] = *(const bf16x8*)&Qh[(size_t)(q0 + nt * 16 + l15) * D_ + kc * 32 + quad * 8];

  f32x4 oacc[2][8];
  #pragma unroll
  for (int i = 0; i < 2; i++)
    #pragma unroll
    for (int j = 0; j < 8; j++) oacc[i][j] = (f32x4){0.f, 0.f, 0.f, 0.f};
  float m_i[2] = {-1e30f, -1e30f}, l_i[2] = {0.f, 0.f};

  // staging geometry
  const int kr_l = lane >> 4;                 // Ks: 4 rows x 16 chunks / instr
  const int vr_l = lane >> 3;                 // Vs: 8 rows x 8 chunks / instr
  const int vcl  = (lane & 7) ^ vr_l;

  for (int t = 0; t < L_; t += 64) {
    __syncthreads();
    #pragma unroll
    for (int ji = 0; ji < 4; ji++) {
      int Rr = wave * 16 + ji * 4;
      int cl = (lane & 15) ^ ((Rr + kr_l) & 15);
      gload_lds16(&Kh[(size_t)(t + Rr + kr_l) * D_ + cl * 8], &Ks[Rr * 128]);
      int R2 = wave * 32 + ji * 8;
      gload_lds16(&Vh[(size_t)(R2 + vr_l) * L_ + t + vcl * 8], &Vs[R2 * 64]);
    }
    __syncthreads();

    // S^T = K Q^T : A = K rows (m=key), B = Q rows (n=q)
    f32x4 s[2][2];
    #pragma unroll
    for (int i = 0; i < 2; i++)
      #pragma unroll
      for (int j = 0; j < 2; j++) s[i][j] = (f32x4){0.f, 0.f, 0.f, 0.f};
    #pragma unroll
    for (int mt = 0; mt < 2; mt++) {
      const int krow = kh * 32 + mt * 16 + l15;
      #pragma unroll
      for (int kc = 0; kc < 4; kc++) {
        bf16x8 kf = *(const bf16x8*)&Ks[krow * 128 + (((kc * 4 + quad) ^ l15) * 8)];
        s[mt][0] = __builtin_amdgcn_mfma_f32_16x16x32_bf16(kf, qf[0][kc], s[mt][0], 0, 0, 0);
        s[mt][1] = __builtin_amdgcn_mfma_f32_16x16x32_bf16(kf, qf[1][kc], s[mt][1], 0, 0, 0);
      }
    }
    // online softmax, stats indexed by q = l15
    float vmax[2], alpha[2], rs[2];
    #pragma unroll
    for (int nt = 0; nt < 2; nt++) {
      vmax[nt] = fmaxf(fmaxf(fmaxf(s[0][nt][0], s[0][nt][1]), fmaxf(s[0][nt][2], s[0][nt][3])),
                       fmaxf(fmaxf(s[1][nt][0], s[1][nt][1]), fmaxf(s[1][nt][2], s[1][nt][3])));
      vmax[nt] = fmaxf(vmax[nt], __shfl_xor(vmax[nt], 16));
      vmax[nt] = fmaxf(vmax[nt], __shfl_xor(vmax[nt], 32));
      float mnew = fmaxf(m_i[nt], vmax[nt]);
      alpha[nt] = __expf(m_i[nt] - mnew);
      m_i[nt] = mnew;
      rs[nt] = 0.f;
    }
    #pragma unroll
    for (int mt = 0; mt < 2; mt++)
      #pragma unroll
      for (int nt = 0; nt < 2; nt++)
        #pragma unroll
        for (int r = 0; r < 4; r++) {
          float p = __expf(s[mt][nt][r] - m_i[nt]);
          s[mt][nt][r] = p;
          rs[nt] += p;
        }
    #pragma unroll
    for (int nt = 0; nt < 2; nt++) {
      rs[nt] += __shfl_xor(rs[nt], 16);
      rs[nt] += __shfl_xor(rs[nt], 32);
      l_i[nt] = l_i[nt] * alpha[nt] + rs[nt];
    }
    // rescale O (rows q=quad*4+r need alpha held at lane l15=q)
    float ar[2][4];
    #pragma unroll
    for (int qt = 0; qt < 2; qt++)
      #pragma unroll
      for (int r = 0; r < 4; r++)
        ar[qt][r] = __shfl(alpha[qt], quad * 4 + r);
    #pragma unroll
    for (int qt = 0; qt < 2; qt++)
      #pragma unroll
      for (int ntd = 0; ntd < 8; ntd++)
        #pragma unroll
        for (int r = 0; r < 4; r++)
          oacc[qt][ntd][r] *= ar[qt][r];
    // pack P into A-frags (register-local: C-layout of S^T == A-layout of P)
    bf16x4 pk[2][2];
    #pragma unroll
    for (int mt = 0; mt < 2; mt++)
      #pragma unroll
      for (int qt = 0; qt < 2; qt++)
        pk[mt][qt] = (bf16x4){(short)f2bf(s[mt][qt][0]), (short)f2bf(s[mt][qt][1]),
                              (short)f2bf(s[mt][qt][2]), (short)f2bf(s[mt][qt][3])};
    // O += P V : B-frags b64 from Vs[d][key]
    #pragma unroll
    for (int ntd = 0; ntd < 8; ntd++) {
      const int vrow = ntd * 16 + l15;
      #pragma unroll
      for (int mt = 0; mt < 2; mt++) {
        int phys = (kh * 4 + mt * 2 + (quad >> 1)) ^ (l15 & 7);
        bf16x4 vf = *(const bf16x4*)&Vs[vrow * 64 + phys * 8 + (quad & 1) * 4];
        oacc[0][ntd] = __builtin_amdgcn_mfma_f32_16x16x16bf16_1k(pk[mt][0], vf, oacc[0][ntd], 0, 0, 0);
        oacc[1][ntd] = __builtin_amdgcn_mfma_f32_16x16x16bf16_1k(pk[mt][1], vf, oacc[1][ntd], 0, 0, 0);
      }
    }
  }

  // ---- merge the two key-halves per q-group
  __syncthreads();
  if (kh == 1) {
    #pragma unroll
    for (int qt = 0; qt < 2; qt++)
      #pragma unroll
      for (int ntd = 0; ntd < 8; ntd++)
        #pragma unroll
        for (int r = 0; r < 4; r++)
          Obuf[(size_t)(qg * 32 + qt * 16 + quad * 4 + r) * 128 + ntd * 16 + l15] = oacc[qt][ntd][r];
    if (quad == 0)
      #pragma unroll
      for (int qt = 0; qt < 2; qt++)
        mlb[qg * 32 + qt * 16 + l15] = make_float2(m_i[qt], l_i[qt]);
  }
  __syncthreads();
  if (kh == 0 && quad == 0) {
    #pragma unroll
    for (int qt = 0; qt < 2; qt++) {
      float2 m1 = mlb[qg * 32 + qt * 16 + l15];
      float M  = fmaxf(m_i[qt], m1.x);
      float a0 = __expf(m_i[qt] - M);
      float a1 = __expf(m1.x - M);
      float Ls = l_i[qt] * a0 + m1.y * a1;
      sAr[qg * 32 + qt * 16 + l15] = make_float4(a0, a1, 1.f / Ls, 0.f);
    }
  }
  __syncthreads();
  if (kh == 0) {
    #pragma unroll
    for (int qt = 0; qt < 2; qt++)
      #pragma unroll
      for (int r = 0; r < 4; r++) {
        float4 A = sAr[qg * 32 + qt * 16 + quad * 4 + r];
        #pragma unroll
        for (int ntd = 0; ntd < 8; ntd++) {
          float o1 = Obuf[(size_t)(qg * 32 + qt * 16 + quad * 4 + r) * 128 + ntd * 16 + l15];
          float v  = (oacc[qt][ntd][r] * A.x + o1 * A.y) * A.z;
          Out[(size_t)(q0 + qt * 16 + quad * 4 + r) * DIM_ + h * D_ + ntd * 16 + l15] = f2bf(v);
        }
      }
  }
}

// ---------------------------------------------------------------- launcher
extern "C" void kernel_launch(void* const* d_in, const int* in_sizes, int n_in,
                              void* d_out, int out_size, void* d_ws, size_t ws_size,
                              hipStream_t stream) {
  const float* x       = (const float*)d_in[0];
  const float* pe      = (const float*)d_in[1];
  const float* w_qkv   = (const float*)d_in[2];
  const float* q_scale = (const float*)d_in[3];
  const float* k_scale = (const float*)d_in[4];
  const float* w_proj  = (const float*)d_in[5];
  const float* b_proj  = (const float*)d_in[6];

  unsigned short* w_qkvT  = (unsigned short*)d_ws;           // [9216][3072]
  unsigned short* w_projT = w_qkvT + 28311552;               // [3072][3072]
  unsigned short* x_b     = w_projT + 9437184;               // [2048][3072]
  unsigned short* qkv_b   = x_b + 6291456;                   // [2048][9216]
  unsigned short* q_r     = qkv_b + 18874368;                // [H][L][D]
  unsigned short* k_r     = q_r + 6291456;
  unsigned short* vt_r    = k_r + 6291456;                   // [H][D][L]
  unsigned short* attn_b  = qkv_b;   // reuse (qkv dead after v_transpose)

  cast_f32_to_bf16<<<2048, 256, 0, stream>>>(x, x_b, 6291456);
  castT_f32_bf16<<<dim3(12, 72), 256, 0, stream>>>(w_qkv, w_qkvT, 3072, 9216);
  castT_f32_bf16<<<dim3(12, 24), 256, 0, stream>>>(w_proj, w_projT, 3072, 3072);

  gemm_bt<true, false><<<dim3(72, 16), 256, 0, stream>>>(
      x_b, w_qkvT, qkv_b, nullptr, 2048, 9216, 3072);

  qkv_post<<<dim3(2048, 24), 128, 0, stream>>>(
      qkv_b, pe, q_scale, k_scale, q_r, k_r);
  v_transpose<<<dim3(8, 24), 256, 0, stream>>>(qkv_b, vt_r);

  flash_attn<<<dim3(32, 24), 256, 0, stream>>>(q_r, k_r, vt_r, attn_b);

  gemm_bt<false, true><<<dim3(24, 16), 256, 0, stream>>>(
      attn_b, w_projT, d_out, b_proj, 2048, 3072, 3072);
}